// Round 2
// baseline (223.088 us; speedup 1.0000x reference)
//
#include <hip/hip_runtime.h>
#include <math.h>

// NeRF volume-rendering aggregation — B=8, R=8192, P=128.
// One wave (64 lanes) per ray; lane l owns samples l and l+64 (split halves)
// so both raw float4 loads and both z loads are PERFECTLY coalesced
// (lane i -> contiguous 16B / 4B). Exclusive cumprod done as two chained
// 64-wide DPP multiplicative scans (low half, then high half seeded with the
// low-half total via v_readlane). Fast transcendentals (__expf, v_rcp_f32).
// Memory-bound target: ~204 MB traffic -> ~33 us at 6.3 TB/s.

#define FAR_DIST 1e10f
#define EPS_V 1e-10f

constexpr int Bv = 8;
constexpr int Rv = 8192;
constexpr int Pv = 128;
constexpr int NRAYS = Bv * Rv;            // 65536
constexpr int WAVES_PER_BLOCK = 4;        // 256 threads

// Output layout (flat, return order):
constexpr int OFF_RGB   = 0;
constexpr int OFF_DEPTH = NRAYS * 3;           // 196608
constexpr int OFF_DISP  = OFF_DEPTH + NRAYS;   // 262144
constexpr int OFF_ALPHA = OFF_DISP + NRAYS;    // 327680
constexpr int OFF_W     = OFF_ALPHA + NRAYS;   // 393216

// ---- DPP helpers (gfx9/CDNA encodings) ----
// row_shr:N = 0x110+N, row_bcast15 = 0x142, row_bcast31 = 0x143.
// bound_ctrl=false + explicit `old` => invalid/masked lanes yield `old`.
template <int ctrl, int rmask>
__device__ __forceinline__ float dpp_mov(float x, float identity) {
    return __int_as_float(__builtin_amdgcn_update_dpp(
        __float_as_int(identity), __float_as_int(x), ctrl, rmask, 0xf, false));
}

// Inclusive multiplicative scan across the 64-lane wave (6 VALU ops).
__device__ __forceinline__ float wave_incl_prod(float x) {
    x *= dpp_mov<0x111, 0xf>(x, 1.0f);  // row_shr:1
    x *= dpp_mov<0x112, 0xf>(x, 1.0f);  // row_shr:2
    x *= dpp_mov<0x114, 0xf>(x, 1.0f);  // row_shr:4
    x *= dpp_mov<0x118, 0xf>(x, 1.0f);  // row_shr:8
    x *= dpp_mov<0x142, 0xa>(x, 1.0f);  // row_bcast15 -> rows 1,3
    x *= dpp_mov<0x143, 0xc>(x, 1.0f);  // row_bcast31 -> rows 2,3
    return x;
}

// Inclusive additive scan; lane 63 ends with the full wave sum.
__device__ __forceinline__ float wave_sum63(float x) {
    x += dpp_mov<0x111, 0xf>(x, 0.0f);
    x += dpp_mov<0x112, 0xf>(x, 0.0f);
    x += dpp_mov<0x114, 0xf>(x, 0.0f);
    x += dpp_mov<0x118, 0xf>(x, 0.0f);
    x += dpp_mov<0x142, 0xa>(x, 0.0f);
    x += dpp_mov<0x143, 0xc>(x, 0.0f);
    return x;
}

// SGPR broadcast of one lane's value to the whole wave (v_readlane).
__device__ __forceinline__ float bcast_lane(float x, int src_lane) {
    return __int_as_float(__builtin_amdgcn_readlane(__float_as_int(x), src_lane));
}

__device__ __forceinline__ float fast_rcp(float x) {
    return __builtin_amdgcn_rcpf(x);
}

__global__ __launch_bounds__(WAVES_PER_BLOCK * 64)
void nerf_agg_kernel(const float* __restrict__ raw,     // (B,R,P,4)
                     const float* __restrict__ zv,      // (B,R,P)
                     const float* __restrict__ rays_d,  // (B,R,3)
                     const float* __restrict__ bg,      // (3,)
                     float* __restrict__ out)
{
    const int lane = threadIdx.x & 63;
    const int wid  = threadIdx.x >> 6;
    const int ray  = blockIdx.x * WAVES_PER_BLOCK + wid;

    // ---- perfectly coalesced loads: lane l owns samples l and l+64 ----
    const float4* raw4 = (const float4*)(raw + (size_t)ray * (Pv * 4));
    const float4 sLo = raw4[lane];           // dense 1KB per instruction
    const float4 sHi = raw4[lane + 64];

    const float* zr = zv + (size_t)ray * Pv;
    const float zLo = zr[lane];              // dense 256B per instruction
    const float zHi = zr[lane + 64];

    const float* rd = rays_d + (size_t)ray * 3;
    const float dx = rd[0], dy = rd[1], dz = rd[2];
    const float nrm = sqrtf(dx * dx + dy * dy + dz * dz);

    // ---- deltas: d(i) = z[i+1]-z[i]; d(127) = FAR; all scaled by |rays_d| ----
    const float znLo_s = __shfl(zLo, (lane + 1) & 63);   // z[lane+1] for lane<63
    const float z64    = bcast_lane(zHi, 0);             // z[64] (lane 63 fixup)
    const float znLo   = (lane == 63) ? z64 : znLo_s;
    const float dLo    = (znLo - zLo) * nrm;

    const float znHi = __shfl(zHi, (lane + 1) & 63);     // z[lane+65] for lane<63
    const float dHi  = ((lane == 63) ? FAR_DIST : (znHi - zHi)) * nrm;

    // ---- alpha & survival u = exp(-relu(sigma)*d) + eps (fast exp) ----
    const float eLo = __expf(-fmaxf(sLo.w, 0.0f) * dLo);
    const float eHi = __expf(-fmaxf(sHi.w, 0.0f) * dHi);
    const float aLo = 1.0f - eLo;
    const float aHi = 1.0f - eHi;
    const float uLo = eLo + EPS_V;
    const float uHi = eHi + EPS_V;

    // ---- exclusive transmittance: two-phase DPP product scan ----
    const float inclLo = wave_incl_prod(uLo);            // prod u[0..lane]
    const float tLo    = inclLo * fast_rcp(uLo);         // prod u[0..lane-1]
    const float T64    = bcast_lane(inclLo, 63);         // prod u[0..63]
    const float inclHi = wave_incl_prod(uHi);            // prod u[64..64+lane]
    const float tHi    = T64 * inclHi * fast_rcp(uHi);   // prod u[0..63+lane]

    const float wLo = aLo * tLo;
    const float wHi = aHi * tHi;

    // ---- store weights (two dense 256B stores) ----
    float* wout = out + OFF_W + (size_t)ray * Pv;
    wout[lane]      = wLo;
    wout[lane + 64] = wHi;

    // ---- rgb = sigmoid(raw[...,0:3]) — fast exp + v_rcp ----
    const float rLo = fast_rcp(1.0f + __expf(-sLo.x));
    const float gLo = fast_rcp(1.0f + __expf(-sLo.y));
    const float bLo = fast_rcp(1.0f + __expf(-sLo.z));
    const float rHi = fast_rcp(1.0f + __expf(-sHi.x));
    const float gHi = fast_rcp(1.0f + __expf(-sHi.y));
    const float bHi = fast_rcp(1.0f + __expf(-sHi.z));

    // ---- 5 wave sums via DPP; totals land in lane 63 ----
    const float rr = wave_sum63(wLo * rLo + wHi * rHi);
    const float gg = wave_sum63(wLo * gLo + wHi * gHi);
    const float bb = wave_sum63(wLo * bLo + wHi * bHi);
    const float sw = wave_sum63(wLo + wHi);
    const float sz = wave_sum63(wLo * zLo + wHi * zHi);

    if (lane == 63) {
        const float c0 = bg[0], c1 = bg[1], c2 = bg[2];
        const bool is_bg = (c0 >= 0.0f && c0 <= 1.0f) &&
                           (c1 >= 0.0f && c1 <= 1.0f) &&
                           (c2 >= 0.0f && c2 <= 1.0f);
        float orr = rr, ogg = gg, obb = bb;
        if (is_bg) {
            const float rem = 1.0f - sw;
            orr += rem * c0;
            ogg += rem * c1;
            obb += rem * c2;
        }
        out[OFF_RGB + 3 * ray + 0] = orr;
        out[OFF_RGB + 3 * ray + 1] = ogg;
        out[OFF_RGB + 3 * ray + 2] = obb;
        out[OFF_DEPTH + ray] = sz;
        out[OFF_ALPHA + ray] = sw;
        out[OFF_DISP + ray] = 1.0f / (fmaxf(sz / sw - EPS_V, 0.0f) + EPS_V);
    }
}

extern "C" void kernel_launch(void* const* d_in, const int* in_sizes, int n_in,
                              void* d_out, int out_size, void* d_ws, size_t ws_size,
                              hipStream_t stream) {
    const float* raw    = (const float*)d_in[0];
    const float* zvals  = (const float*)d_in[1];
    const float* rays_d = (const float*)d_in[2];
    const float* bg     = (const float*)d_in[3];
    float* out = (float*)d_out;

    const int blocks = NRAYS / WAVES_PER_BLOCK; // 16384
    nerf_agg_kernel<<<blocks, WAVES_PER_BLOCK * 64, 0, stream>>>(raw, zvals, rays_d, bg, out);
}